// Round 1
// baseline (4329.181 us; speedup 1.0000x reference)
//
#include <hip/hip_runtime.h>
#include <math.h>

// Problem constants (match reference)
constexpr int Bq  = 256;
constexpr int S1q = 512;
constexpr int S2q = 64;
constexpr int Hq  = 768;
constexpr int OPCq = 64;
constexpr int OTq  = 128;   // OPC + S2
#define NEGq (-1e12f)

// Output layout (flat f32 concat):
//  num_score [256,128]      @ 0        (32768)
//  node      [256,1,768]    @ 32768    (196608)
//  context   [256,1,768]    @ 229376   (196608)
//  emb_all   [256,128,768]  @ 425984   (25165824)

__device__ __forceinline__ float fast_tanh(float x) {
    x = fminf(fmaxf(x, -15.f), 15.f);
    float e = __expf(2.f * x);
    return (e - 1.f) / (e + 1.f);
}
__device__ __forceinline__ float fast_sigmoid(float x) {
    x = fminf(fmaxf(x, -30.f), 30.f);
    return 1.f / (1.f + __expf(-x));
}

// ---------------------------------------------------------------------------
// K1: node[b,h] = select(has_left, tanh(lc@W_r+b_r)*sig(lc@W_rg+b_rg),
//                                 tanh(cur@W_l+b_l)*sig(cur@W_lg+b_lg))
// grid (H/256, B/BT), block 256. BT rows staged in LDS, W columns coalesced.
// ---------------------------------------------------------------------------
template <int BT>
__global__ __launch_bounds__(256)
void node_kernel(const float* __restrict__ cur_emb, const float* __restrict__ left_emb,
                 const float* __restrict__ W_l,  const float* __restrict__ b_l,
                 const float* __restrict__ W_lg, const float* __restrict__ b_lg,
                 const float* __restrict__ W_r,  const float* __restrict__ b_r,
                 const float* __restrict__ W_rg, const float* __restrict__ b_rg,
                 const int* __restrict__ has_left, float* __restrict__ node_out) {
    __shared__ float lcs[BT][2 * Hq];   // [left | current]
    const int tid = threadIdx.x;
    const int h  = blockIdx.x * 256 + tid;
    const int b0 = blockIdx.y * BT;
    for (int idx = tid; idx < BT * Hq; idx += 256) {
        int j = idx / Hq, k = idx % Hq;
        lcs[j][k]      = left_emb[(b0 + j) * Hq + k];
        lcs[j][Hq + k] = cur_emb[(b0 + j) * Hq + k];
    }
    __syncthreads();
    float agl[BT], atl[BT], agr[BT], atr[BT];
#pragma unroll
    for (int j = 0; j < BT; j++) { agl[j] = b_l[h]; atl[j] = b_lg[h]; agr[j] = b_r[h]; atr[j] = b_rg[h]; }
    for (int k = 0; k < Hq; k++) {
        float wl = W_l[k * Hq + h], wlg = W_lg[k * Hq + h];
#pragma unroll
        for (int j = 0; j < BT; j++) { float x = lcs[j][Hq + k]; agl[j] += x * wl; atl[j] += x * wlg; }
    }
    for (int k = 0; k < 2 * Hq; k++) {
        float wr = W_r[k * Hq + h], wrg = W_rg[k * Hq + h];
#pragma unroll
        for (int j = 0; j < BT; j++) { float x = lcs[j][k]; agr[j] += x * wr; atr[j] += x * wrg; }
    }
#pragma unroll
    for (int j = 0; j < BT; j++) {
        int b = b0 + j;
        float n = has_left[b] ? fast_tanh(agr[j]) * fast_sigmoid(atr[j])
                              : fast_tanh(agl[j]) * fast_sigmoid(atl[j]);
        node_out[b * Hq + h] = n;
    }
}

// ---------------------------------------------------------------------------
// K2 (generic): out[m,h] = bias[h] + A1[m,:K1]@W[0:K1, h] + A2[m,:K2]@W[K1:K1+K2, h]
// Used for nodeproj (node@W_attn[:H]+b_attn), scorebase ([node,ctx]@W_score[:2H]+b_score),
// opproj (emb_op_const@W_score[2H:]).
// ---------------------------------------------------------------------------
template <int BT>
__global__ __launch_bounds__(256)
void proj_kernel(const float* __restrict__ A1, const float* __restrict__ A2,
                 int K1, int K2,
                 const float* __restrict__ W, const float* __restrict__ bias,
                 float* __restrict__ out) {
    __shared__ float As[BT][2 * Hq];
    const int tid = threadIdx.x;
    const int h  = blockIdx.x * 256 + tid;
    const int b0 = blockIdx.y * BT;
    const int K = K1 + K2;
    for (int idx = tid; idx < BT * K1; idx += 256) {
        int j = idx / K1, k = idx % K1;
        As[j][k] = A1[(b0 + j) * K1 + k];
    }
    if (A2) {
        for (int idx = tid; idx < BT * K2; idx += 256) {
            int j = idx / K2, k = idx % K2;
            As[j][K1 + k] = A2[(b0 + j) * K2 + k];
        }
    }
    __syncthreads();
    float acc[BT];
#pragma unroll
    for (int j = 0; j < BT; j++) acc[j] = bias ? bias[h] : 0.f;
    for (int k = 0; k < K; k++) {
        float w = W[k * Hq + h];
#pragma unroll
        for (int j = 0; j < BT; j++) acc[j] += As[j][k] * w;
    }
#pragma unroll
    for (int j = 0; j < BT; j++) out[(b0 + j) * Hq + h] = acc[j];
}

// ---------------------------------------------------------------------------
// K3 (generic fused): out[row] = sum_h v[h] * tanh( (A[row,:]@W)[h] + addv[b,h] )
// optionally masked to NEG. Rows per block: 64, full H=768 column sweep in
// tiles of 64. 16 accs/thread (4 rows x 4 cols), LDS-staged A (transposed,
// pitch 68) and W (pitch 68).
//   b = row >> shift   (blocks never straddle b: 64 | S1 and 64 | S2)
//   out index = b*ostride + ooff + (row - b<<shift); mask uses same index.
// ---------------------------------------------------------------------------
__global__ __launch_bounds__(256)
void fused_tanh_dot_kernel(const float* __restrict__ A,    // [M, 768]
                           const float* __restrict__ W,    // [768, 768] (row-offset applied by caller)
                           const float* __restrict__ addv, // [nb, 768]
                           const float* __restrict__ v,    // [768]
                           float* __restrict__ out,
                           const int* __restrict__ maskp,  // nullable
                           int shift, int ostride, int ooff) {
    __shared__ float Asm[64 * 68];  // [k][row], pitch 68 (16B aligned, bank-spread)
    __shared__ float Wsm[64 * 68];  // [k][col], pitch 68
    const int tid = threadIdx.x;
    const int tx = tid & 15, ty = tid >> 4;
    const int rowbase = blockIdx.x * 64;
    const int b = rowbase >> shift;
    const float* Arow = A + (size_t)rowbase * Hq;
    float epart[4] = {0.f, 0.f, 0.f, 0.f};
    const int sr = tid & 63;   // A staging: row
    const int sc = tid >> 6;   // A staging: 16-float chunk
    const int wk = tid >> 2;   // W staging: k
    const int wc = tid & 3;    // W staging: 16-float chunk

    for (int ct = 0; ct < 12; ct++) {
        const int hb = ct * 64;
        float acc[4][4] = {};
        for (int kt = 0; kt < 12; kt++) {
            const int kb = kt * 64;
            __syncthreads();
            // stage A tile transposed: Asm[k*68 + r]
#pragma unroll
            for (int u = 0; u < 4; u++) {
                float4 a4 = *(const float4*)&Arow[(size_t)sr * Hq + kb + sc * 16 + u * 4];
                int k0 = sc * 16 + u * 4;
                Asm[(k0 + 0) * 68 + sr] = a4.x;
                Asm[(k0 + 1) * 68 + sr] = a4.y;
                Asm[(k0 + 2) * 68 + sr] = a4.z;
                Asm[(k0 + 3) * 68 + sr] = a4.w;
            }
            // stage W tile: Wsm[k*68 + c]
#pragma unroll
            for (int u = 0; u < 4; u++) {
                float4 w4 = *(const float4*)&W[(size_t)(kb + wk) * Hq + hb + wc * 16 + u * 4];
                *(float4*)&Wsm[wk * 68 + wc * 16 + u * 4] = w4;
            }
            __syncthreads();
#pragma unroll 16
            for (int kk = 0; kk < 64; kk++) {
                float4 a4 = *(const float4*)&Asm[kk * 68 + ty * 4];
                float4 w4 = *(const float4*)&Wsm[kk * 68 + tx * 4];
                float av[4] = {a4.x, a4.y, a4.z, a4.w};
                float wv[4] = {w4.x, w4.y, w4.z, w4.w};
#pragma unroll
                for (int i = 0; i < 4; i++)
#pragma unroll
                    for (int c = 0; c < 4; c++) acc[i][c] += av[i] * wv[c];
            }
        }
        // epilogue for this column tile: add addv, tanh, dot with v
        const float* ad = addv + (size_t)b * Hq + hb;
#pragma unroll
        for (int i = 0; i < 4; i++) {
            float s = 0.f;
#pragma unroll
            for (int c = 0; c < 4; c++) {
                int hh = tx * 4 + c;
                s += v[hb + hh] * fast_tanh(acc[i][c] + ad[hh]);
            }
            epart[i] += s;
        }
    }
    // reduce across the 16 tx lanes (contiguous lanes within the wave)
#pragma unroll
    for (int i = 0; i < 4; i++) {
        float s = epart[i];
        s += __shfl_down(s, 8, 16);
        s += __shfl_down(s, 4, 16);
        s += __shfl_down(s, 2, 16);
        s += __shfl_down(s, 1, 16);
        epart[i] = s;
    }
    if (tx == 0) {
#pragma unroll
        for (int i = 0; i < 4; i++) {
            int row = rowbase + ty * 4 + i;
            int j = row - (b << shift);
            int oidx = b * ostride + ooff + j;
            float val = epart[i];
            if (maskp && maskp[oidx]) val = NEGq;
            out[oidx] = val;
        }
    }
}

// ---------------------------------------------------------------------------
// K4: masked softmax over S1 per b, in place (energy -> attn)
// ---------------------------------------------------------------------------
__global__ __launch_bounds__(256)
void softmax_kernel(float* __restrict__ e, const int* __restrict__ smask) {
    __shared__ float red[256];
    const int b = blockIdx.x, tid = threadIdx.x;
    float e0 = e[b * S1q + tid], e1 = e[b * S1q + 256 + tid];
    if (smask[b * S1q + tid]) e0 = NEGq;
    if (smask[b * S1q + 256 + tid]) e1 = NEGq;
    red[tid] = fmaxf(e0, e1);
    __syncthreads();
    for (int off = 128; off > 0; off >>= 1) {
        if (tid < off) red[tid] = fmaxf(red[tid], red[tid + off]);
        __syncthreads();
    }
    float mx = red[0];
    __syncthreads();
    float p0 = __expf(e0 - mx), p1 = __expf(e1 - mx);
    red[tid] = p0 + p1;
    __syncthreads();
    for (int off = 128; off > 0; off >>= 1) {
        if (tid < off) red[tid] += red[tid + off];
        __syncthreads();
    }
    float inv = 1.f / red[0];
    e[b * S1q + tid] = p0 * inv;
    e[b * S1q + 256 + tid] = p1 * inv;
}

// ---------------------------------------------------------------------------
// K5: context[b,h] = sum_s attn[b,s] * enc[b,s,h]
// ---------------------------------------------------------------------------
__global__ __launch_bounds__(256)
void context_kernel(const float* __restrict__ attn, const float* __restrict__ enc,
                    float* __restrict__ ctx_out) {
    __shared__ float attn_s[S1q];
    const int tid = threadIdx.x;
    const int b = blockIdx.y;
    const int h = blockIdx.x * 256 + tid;
    attn_s[tid]       = attn[b * S1q + tid];
    attn_s[256 + tid] = attn[b * S1q + 256 + tid];
    __syncthreads();
    float c = 0.f;
    const float* ep = enc + (size_t)b * S1q * Hq + h;
    for (int s = 0; s < S1q; s++) c += attn_s[s] * ep[(size_t)s * Hq];
    ctx_out[b * Hq + h] = c;
}

// ---------------------------------------------------------------------------
// K6: op/const scores: num_score[b,o<64] = mask? NEG : v . tanh(scorebase[b]+opproj[o])
// block per b; thread = (o = tid&63, q = tid>>6) quarter-of-H partials.
// ---------------------------------------------------------------------------
__global__ __launch_bounds__(256)
void opscore_kernel(const float* __restrict__ scorebase, const float* __restrict__ opproj,
                    const float* __restrict__ vsc, const int* __restrict__ cmask,
                    float* __restrict__ num_score) {
    __shared__ float sb[Hq];
    __shared__ float red[256];
    const int b = blockIdx.x, tid = threadIdx.x;
    for (int i = tid; i < Hq; i += 256) sb[i] = scorebase[b * Hq + i];
    __syncthreads();
    const int o = tid & 63, q = tid >> 6;
    float part = 0.f;
    for (int h = q * 192; h < (q + 1) * 192; h++)
        part += vsc[h] * fast_tanh(sb[h] + opproj[o * Hq + h]);
    red[tid] = part;
    __syncthreads();
    if (tid < 64) {
        float val = red[tid] + red[tid + 64] + red[tid + 128] + red[tid + 192];
        int oidx = b * OTq + tid;
        num_score[oidx] = cmask[oidx] ? NEGq : val;
    }
}

// ---------------------------------------------------------------------------
// K7: emb_all = concat(broadcast(emb_op_const), var_pades) — pure copy, float4
// ---------------------------------------------------------------------------
__global__ __launch_bounds__(256)
void emb_all_kernel(const float* __restrict__ opc, const float* __restrict__ var,
                    float4* __restrict__ out) {
    const long long total = (long long)Bq * OTq * (Hq / 4);
    for (long long idx = (long long)blockIdx.x * 256 + threadIdx.x; idx < total;
         idx += (long long)gridDim.x * 256) {
        long long b = idx / (OTq * (Hq / 4));
        int rem = (int)(idx - b * (OTq * (Hq / 4)));
        int o = rem / (Hq / 4), hv = rem % (Hq / 4);
        float4 val;
        if (o < OPCq) val = *(const float4*)&opc[o * Hq + hv * 4];
        else          val = *(const float4*)&var[((b * S2q) + (o - OPCq)) * (long long)Hq + hv * 4];
        out[idx] = val;
    }
}

extern "C" void kernel_launch(void* const* d_in, const int* in_sizes, int n_in,
                              void* d_out, int out_size, void* d_ws, size_t ws_size,
                              hipStream_t stream) {
    const float* cur     = (const float*)d_in[0];
    const float* left    = (const float*)d_in[1];
    const float* enc     = (const float*)d_in[2];
    const float* var     = (const float*)d_in[3];
    const float* opc     = (const float*)d_in[4];
    const float* W_l     = (const float*)d_in[5];
    const float* b_l     = (const float*)d_in[6];
    const float* W_lg    = (const float*)d_in[7];
    const float* b_lg    = (const float*)d_in[8];
    const float* W_r     = (const float*)d_in[9];
    const float* b_r     = (const float*)d_in[10];
    const float* W_rg    = (const float*)d_in[11];
    const float* b_rg    = (const float*)d_in[12];
    const float* W_attn  = (const float*)d_in[13];
    const float* b_attn  = (const float*)d_in[14];
    const float* v_attn  = (const float*)d_in[15];
    const float* W_score = (const float*)d_in[16];
    const float* b_score = (const float*)d_in[17];
    const float* v_score = (const float*)d_in[18];
    const int*   has_left= (const int*)d_in[19];
    const int*   smask   = (const int*)d_in[20];
    const int*   cmask   = (const int*)d_in[21];

    float* out       = (float*)d_out;
    float* num_score = out;            // [256,128]
    float* node      = out + 32768;    // [256,768]
    float* context   = out + 229376;   // [256,768]
    float* emb_all   = out + 425984;   // [256,128,768]

    float* ws        = (float*)d_ws;
    float* nodeproj  = ws;                       // 196608 f32
    float* energy    = ws + 196608;              // 131072 f32 (becomes attn in place)
    float* scorebase = ws + 196608 + 131072;     // 196608 f32
    float* opproj    = scorebase + 196608;       // 49152 f32
    // total ws use: 573440 f32 = 2.19 MB

    // 1. node
    node_kernel<8><<<dim3(3, 32), 256, 0, stream>>>(cur, left, W_l, b_l, W_lg, b_lg,
                                                    W_r, b_r, W_rg, b_rg, has_left, node);
    // 2. nodeproj = node @ W_attn[:768] + b_attn
    proj_kernel<8><<<dim3(3, 32), 256, 0, stream>>>(node, nullptr, 768, 0, W_attn, b_attn, nodeproj);
    // 3. opproj = emb_op_const @ W_score[1536:2304]   (batch-independent!)
    proj_kernel<8><<<dim3(3, 8), 256, 0, stream>>>(opc, nullptr, 768, 0,
                                                   W_score + (size_t)1536 * Hq, nullptr, opproj);
    // 4. energy[b,s] = v_attn . tanh(nodeproj[b] + enc[b,s]@W_attn[768:1536])
    fused_tanh_dot_kernel<<<2048, 256, 0, stream>>>(enc, W_attn + (size_t)768 * Hq, nodeproj,
                                                    v_attn, energy, nullptr, 9, S1q, 0);
    // 5. masked softmax (in place -> attn)
    softmax_kernel<<<256, 256, 0, stream>>>(energy, smask);
    // 6. context
    context_kernel<<<dim3(3, 256), 256, 0, stream>>>(energy, enc, context);
    // 7. scorebase = [node, context] @ W_score[:1536] + b_score
    proj_kernel<8><<<dim3(3, 32), 256, 0, stream>>>(node, context, 768, 768, W_score, b_score, scorebase);
    // 8. var scores -> num_score[:, 64:128] with candi_mask
    fused_tanh_dot_kernel<<<256, 256, 0, stream>>>(var, W_score + (size_t)1536 * Hq, scorebase,
                                                   v_score, num_score, cmask, 6, OTq, OPCq);
    // 9. op/const scores -> num_score[:, 0:64] with candi_mask
    opscore_kernel<<<256, 256, 0, stream>>>(scorebase, opproj, v_score, cmask, num_score);
    // 10. emb_all copy-out
    emb_all_kernel<<<4096, 256, 0, stream>>>(opc, var, (float4*)emb_all);
}